// Round 2
// baseline (86.060 us; speedup 1.0000x reference)
//
#include <hip/hip_runtime.h>
#include <math.h>

// Problem constants (from setup_inputs): B=4, C=4, H=96, W=96
#define BB 4
#define CC 4
#define HH 96
#define WW 96
#define NN (HH * WW)
#define BIGF 1e10f
#define HALF_ROWS (HH / 2)

// ---------------------------------------------------------------------------
// K1: one block per (batch b, direction e, row-half h).  blk = b*4 + e*2 + h
//   e=0: EDT of maskP, masked max over maskT pixels (bwd direction)
//   e=1: EDT of maskT, masked max over maskP pixels (fwd direction)
// All intermediates in LDS. Writes one partial max per block to ws.
// ---------------------------------------------------------------------------
__global__ __launch_bounds__(1024) void k_fused(const float* __restrict__ out,
                                                const int* __restrict__ tgt,
                                                float* __restrict__ partial) {
    __shared__ __align__(16) float g[NN];        // 36864 B: column-EDT result
    __shared__ unsigned char predL[NN];          //  9216 B: argmax labels
    __shared__ unsigned char maskE[NN];          //  9216 B: EDT source mask
    __shared__ unsigned char maskO[NN];          //  9216 B: max-over mask
    __shared__ float red[16];                    // cross-wave reduce
    // total 64,576 B (< 64 KiB static limit)

    const int blk = blockIdx.x;
    const int h = blk & 1;
    const int e = (blk >> 1) & 1;
    const int b = blk >> 2;
    const int tid = threadIdx.x;

    // ---- P1: pred = argmax over C (first-max semantics: strict >) ----
    const float* obase = out + (size_t)b * CC * NN;
    for (int p = tid; p < NN; p += 1024) {
        float v0 = obase[p];
        float v1 = obase[NN + p];
        float v2 = obase[2 * NN + p];
        float v3 = obase[3 * NN + p];
        int bc = 0; float bv = v0;
        if (v1 > bv) { bv = v1; bc = 1; }
        if (v2 > bv) { bv = v2; bc = 2; }
        if (v3 > bv) { bv = v3; bc = 3; }
        predL[p] = (unsigned char)bc;
    }
    __syncthreads();

    // ---- P2: boundary masks (any in-bounds 4-neighbor differs) ----
    const int* tbase = tgt + b * NN;
    for (int p = tid; p < NN; p += 1024) {
        int i = p / WW;
        int j = p - i * WW;
        int vp = predL[p];
        bool bP = false;
        if (i > 0)      bP |= (predL[p - WW] != vp);
        if (i < HH - 1) bP |= (predL[p + WW] != vp);
        if (j > 0)      bP |= (predL[p - 1]  != vp);
        if (j < WW - 1) bP |= (predL[p + 1]  != vp);
        int vt = tbase[p];
        bool bT = false;
        if (i > 0)      bT |= (tbase[p - WW] != vt);
        if (i < HH - 1) bT |= (tbase[p + WW] != vt);
        if (j > 0)      bT |= (tbase[p - 1]  != vt);
        if (j < WW - 1) bT |= (tbase[p + 1]  != vt);
        unsigned char mp = bP ? 1 : 0;
        unsigned char mt = bT ? 1 : 0;
        maskE[p] = e ? mt : mp;
        maskO[p] = e ? mp : mt;
    }
    __syncthreads();

    // ---- P3: column EDT, O(H) two-pass scan (thread j owns column j) ----
    if (tid < WW) {
        const int j = tid;
        int last = -2000;
        for (int i = 0; i < HH; ++i) {
            if (maskE[i * WW + j]) last = i;
            int d = i - last;                     // real d <= 95; sentinel > 1000
            g[i * WW + j] = (d < 1000) ? (float)(d * d) : BIGF;
        }
        int lastb = 4000;
        for (int i = HH - 1; i >= 0; --i) {
            if (maskE[i * WW + j]) lastb = i;
            int d = lastb - i;
            if (d < 1000) g[i * WW + j] = fminf(g[i * WW + j], (float)(d * d));
        }
    }
    __syncthreads();

    // ---- P4: row pass (exact sq. EDT) fused with masked max over maskO ----
    float m = -BIGF;
    const int pix0 = h * HALF_ROWS * WW;          // this block's 4608 pixels
    for (int p4 = tid; p4 < HALF_ROWS * WW; p4 += 1024) {
        int p = pix0 + p4;
        int i = p / WW;
        int j = p - i * WW;
        const float* grow = &g[i * WW];
        float best = BIGF;
        float d0 = (float)j;                      // j - jp, jp starts at 0
        #pragma unroll 6
        for (int jp = 0; jp < WW; jp += 4) {
            float4 gv = *(const float4*)(grow + jp);   // ds_read_b128, broadcast-heavy
            float a0 = d0;        best = fminf(best, fmaf(a0, a0, gv.x));
            float a1 = d0 - 1.f;  best = fminf(best, fmaf(a1, a1, gv.y));
            float a2 = d0 - 2.f;  best = fminf(best, fmaf(a2, a2, gv.z));
            float a3 = d0 - 3.f;  best = fminf(best, fmaf(a3, a3, gv.w));
            d0 -= 4.0f;
        }
        if (maskO[p]) m = fmaxf(m, best);
    }
    // block max-reduce
    #pragma unroll
    for (int off = 32; off > 0; off >>= 1) m = fmaxf(m, __shfl_down(m, off));
    const int wid = tid >> 6, lid = tid & 63;
    if (lid == 0) red[wid] = m;
    __syncthreads();
    if (tid == 0) {
        float mm = red[0];
        #pragma unroll
        for (int w = 1; w < 16; ++w) mm = fmaxf(mm, red[w]);
        partial[blk] = mm;
    }
}

// ---------------------------------------------------------------------------
// K2: combine 16 partials -> mean over batches of sqrt(max(fwd,bwd,0))
// ---------------------------------------------------------------------------
__global__ void k_fin(const float* __restrict__ partial, float* __restrict__ outv) {
    if (threadIdx.x == 0) {
        float s = 0.0f;
        #pragma unroll
        for (int b = 0; b < BB; ++b) {
            float bwd = fmaxf(partial[b * 4 + 0], partial[b * 4 + 1]);  // e=0 halves
            float fwd = fmaxf(partial[b * 4 + 2], partial[b * 4 + 3]);  // e=1 halves
            s += sqrtf(fmaxf(fmaxf(fwd, bwd), 0.0f));
        }
        outv[0] = s * 0.25f;
    }
}

// ---------------------------------------------------------------------------
extern "C" void kernel_launch(void* const* d_in, const int* in_sizes, int n_in,
                              void* d_out, int out_size, void* d_ws, size_t ws_size,
                              hipStream_t stream) {
    const float* output = (const float*)d_in[0];   // [B,C,H,W] fp32
    const int* target   = (const int*)d_in[1];     // [B,H,W] int32
    float* outv         = (float*)d_out;           // scalar fp32
    float* partial      = (float*)d_ws;            // 16 floats

    k_fused<<<16, 1024, 0, stream>>>(output, target, partial);
    k_fin<<<1, 64, 0, stream>>>(partial, outv);
}

// Round 3
// 74.961 us; speedup vs baseline: 1.1481x; 1.1481x over previous
//
#include <hip/hip_runtime.h>
#include <math.h>

// Problem constants (from setup_inputs): B=4, C=4, H=96, W=96
#define BB 4
#define CC 4
#define HH 96
#define WW 96
#define NN (HH * WW)
#define BIGF 1e10f
#define QROWS (HH / 4)   // 24 rows per block quarter

// ---------------------------------------------------------------------------
// K1: one block per (batch b, direction e, quarter q). blk = b*8 + e*4 + q
//   e=0: EDT of maskP, masked max over maskT pixels (bwd)
//   e=1: EDT of maskT, masked max over maskP pixels (fwd)
// All intermediates in LDS. Column EDT via per-column 96-bit masks + clz/ffs
// (fully parallel — no serial scan). Writes one partial max per block.
// ---------------------------------------------------------------------------
__global__ __launch_bounds__(1024) void k_fused(const float* __restrict__ out,
                                                const int* __restrict__ tgt,
                                                float* __restrict__ partial) {
    // manual LDS carve: 64,512 B total (<= 64 KiB static limit)
    __shared__ __align__(16) unsigned char smem[64512];
    float* g              = (float*)smem;                 // 36864 B
    unsigned char* maskE  = smem + 36864;                 //  9216 B
    unsigned char* maskO  = smem + 46080;                 //  9216 B
    unsigned char* scratch = smem + 55296;                //  9216 B (predL, then colbits+red)
    unsigned char* predL  = scratch;                      // 9216 B (dead after P2)
    unsigned int* colbits = (unsigned int*)scratch;       // 96*5*4 = 1920 B (stride 5: no conflicts)
    float* red            = (float*)(scratch + 2048);     // 16 floats

    const int blk = blockIdx.x;
    const int q = blk & 3;
    const int e = (blk >> 2) & 1;
    const int b = blk >> 3;
    const int tid = threadIdx.x;

    // ---- P1: pred = argmax over C (first-max semantics: strict >) ----
    const float* obase = out + (size_t)b * CC * NN;
    for (int p = tid; p < NN; p += 1024) {
        float v0 = obase[p];
        float v1 = obase[NN + p];
        float v2 = obase[2 * NN + p];
        float v3 = obase[3 * NN + p];
        int bc = 0; float bv = v0;
        if (v1 > bv) { bv = v1; bc = 1; }
        if (v2 > bv) { bv = v2; bc = 2; }
        if (v3 > bv) { bv = v3; bc = 3; }
        predL[p] = (unsigned char)bc;
    }
    __syncthreads();

    // ---- P2: boundary masks (any in-bounds 4-neighbor differs) ----
    const int* tbase = tgt + b * NN;
    for (int p = tid; p < NN; p += 1024) {
        int i = p / WW;
        int j = p - i * WW;
        int vp = predL[p];
        bool bP = false;
        if (i > 0)      bP |= (predL[p - WW] != vp);
        if (i < HH - 1) bP |= (predL[p + WW] != vp);
        if (j > 0)      bP |= (predL[p - 1]  != vp);
        if (j < WW - 1) bP |= (predL[p + 1]  != vp);
        int vt = tbase[p];
        bool bT = false;
        if (i > 0)      bT |= (tbase[p - WW] != vt);
        if (i < HH - 1) bT |= (tbase[p + WW] != vt);
        if (j > 0)      bT |= (tbase[p - 1]  != vt);
        if (j < WW - 1) bT |= (tbase[p + 1]  != vt);
        unsigned char mp = bP ? 1 : 0;
        unsigned char mt = bT ? 1 : 0;
        maskE[p] = e ? mt : mp;
        maskO[p] = e ? mp : mt;
    }
    __syncthreads();   // maskE/maskO ready; predL dead from here

    // ---- P3a: pack columns of maskE into bitmasks (3 u32 words / column) ----
    if (tid < 96 * 3) {
        int j = tid / 3, w = tid - j * 3;
        const unsigned char* colp = &maskE[w * 32 * WW + j];
        unsigned int bits = 0;
        #pragma unroll
        for (int r = 0; r < 32; ++r) bits |= ((unsigned int)colp[r * WW]) << r;
        colbits[j * 5 + w] = bits;
    }
    __syncthreads();

    // ---- P3b: column EDT, O(1)/pixel via clz/ffs on the column bitmask ----
    for (int p = tid; p < NN; p += 1024) {
        int i = p / WW;
        int j = p - i * WW;
        unsigned int w0 = colbits[j * 5 + 0];
        unsigned int w1 = colbits[j * 5 + 1];
        unsigned int hi = colbits[j * 5 + 2];
        unsigned long long lo = (unsigned long long)w0 | ((unsigned long long)w1 << 32);
        int up = 1 << 20, dn = 1 << 20;
        if (i < 64) {
            unsigned long long mu = lo & (~0ull >> (63 - i));          // rows 0..i
            if (mu) up = i - (63 - __clzll(mu));
            unsigned long long md = lo >> i;                           // rows i..63
            if (md) dn = __ffsll(md) - 1;
            else if (hi) dn = (64 - i) + (__ffs(hi) - 1);
        } else {
            int ih = i - 64;
            unsigned int mu = hi & (0xffffffffu >> (31 - ih));         // rows 64..i
            if (mu) up = ih - (31 - __clz(mu));
            else if (lo) up = i - (63 - __clzll(lo));
            unsigned int md = hi >> ih;                                // rows i..95
            if (md) dn = __ffs(md) - 1;
        }
        int d = (up < dn) ? up : dn;
        g[p] = (d < HH) ? (float)(d * d) : BIGF;
    }
    __syncthreads();

    // ---- P4: row pass (exact sq. EDT) fused with masked max over maskO ----
    float m = -BIGF;
    const int pix0 = q * QROWS * WW;          // this block's 2304 pixels
    for (int p4 = tid; p4 < QROWS * WW; p4 += 1024) {
        int p = pix0 + p4;
        int i = p / WW;
        int j = p - i * WW;
        const float* grow = &g[i * WW];
        float best = BIGF;
        float d0 = (float)j;                   // j - jp, jp starts at 0
        #pragma unroll 6
        for (int jp = 0; jp < WW; jp += 4) {
            float4 gv = *(const float4*)(grow + jp);   // broadcast-heavy ds_read_b128
            float a0 = d0;        best = fminf(best, fmaf(a0, a0, gv.x));
            float a1 = d0 - 1.f;  best = fminf(best, fmaf(a1, a1, gv.y));
            float a2 = d0 - 2.f;  best = fminf(best, fmaf(a2, a2, gv.z));
            float a3 = d0 - 3.f;  best = fminf(best, fmaf(a3, a3, gv.w));
            d0 -= 4.0f;
        }
        if (maskO[p]) m = fmaxf(m, best);
    }
    // block max-reduce (16 waves)
    #pragma unroll
    for (int off = 32; off > 0; off >>= 1) m = fmaxf(m, __shfl_down(m, off));
    const int wid = tid >> 6, lid = tid & 63;
    if (lid == 0) red[wid] = m;
    __syncthreads();
    if (tid == 0) {
        float mm = red[0];
        #pragma unroll
        for (int w = 1; w < 16; ++w) mm = fmaxf(mm, red[w]);
        partial[blk] = mm;
    }
}

// ---------------------------------------------------------------------------
// K2: combine 32 partials -> mean over batches of sqrt(max(fwd,bwd,0))
// ---------------------------------------------------------------------------
__global__ void k_fin(const float* __restrict__ partial, float* __restrict__ outv) {
    if (threadIdx.x == 0) {
        float s = 0.0f;
        #pragma unroll
        for (int b = 0; b < BB; ++b) {
            float bwd = -BIGF, fwd = -BIGF;
            #pragma unroll
            for (int qq = 0; qq < 4; ++qq) {
                bwd = fmaxf(bwd, partial[b * 8 + qq]);       // e=0 quarters
                fwd = fmaxf(fwd, partial[b * 8 + 4 + qq]);   // e=1 quarters
            }
            s += sqrtf(fmaxf(fmaxf(fwd, bwd), 0.0f));
        }
        outv[0] = s * 0.25f;
    }
}

// ---------------------------------------------------------------------------
extern "C" void kernel_launch(void* const* d_in, const int* in_sizes, int n_in,
                              void* d_out, int out_size, void* d_ws, size_t ws_size,
                              hipStream_t stream) {
    const float* output = (const float*)d_in[0];   // [B,C,H,W] fp32
    const int* target   = (const int*)d_in[1];     // [B,H,W] int32
    float* outv         = (float*)d_out;           // scalar fp32
    float* partial      = (float*)d_ws;            // 32 floats

    k_fused<<<32, 1024, 0, stream>>>(output, target, partial);
    k_fin<<<1, 64, 0, stream>>>(partial, outv);
}